// Round 1
// baseline (892.959 us; speedup 1.0000x reference)
//
#include <hip/hip_runtime.h>

typedef __bf16 bf16x8 __attribute__((ext_vector_type(8)));
typedef float f32x4 __attribute__((ext_vector_type(4)));

constexpr int NB   = 2;      // batch
constexpr int SEQ  = 2048;   // sequence
constexpr int DM   = 2048;   // d_model
constexpr int NH   = 16;     // heads
constexpr int HD   = 128;    // head dim
constexpr int DL   = 512;    // d_latent
constexpr int ROWS = NB * SEQ; // 4096

// ---------------------------------------------------------------- cast f32->bf16
__global__ __launch_bounds__(256) void cast_bf16(const float* __restrict__ in,
                                                 __bf16* __restrict__ out, int n4) {
  int i = blockIdx.x * blockDim.x + threadIdx.x;
  int stride = gridDim.x * blockDim.x;
  for (int k = i; k < n4; k += stride) {
    float4 v = ((const float4*)in)[k];
    union { __bf16 h[4]; uint2 u; } uo;
    uo.h[0] = (__bf16)v.x; uo.h[1] = (__bf16)v.y;
    uo.h[2] = (__bf16)v.z; uo.h[3] = (__bf16)v.w;
    ((uint2*)out)[k] = uo.u;
  }
}

// ------------------------------------------------- tiled transpose + cast f32->bf16
// out[c][r] = in[r][c];  grid (C/32, R/32), block (32,8)
__global__ __launch_bounds__(256) void transpose_cast(const float* __restrict__ in,
                                                      __bf16* __restrict__ out,
                                                      int R, int C) {
  __shared__ float t[32][33];
  int r0 = blockIdx.y * 32, c0 = blockIdx.x * 32;
  int tx = threadIdx.x, ty = threadIdx.y;
#pragma unroll
  for (int i = 0; i < 4; ++i)
    t[ty + 8*i][tx] = in[(size_t)(r0 + ty + 8*i) * C + c0 + tx];
  __syncthreads();
#pragma unroll
  for (int i = 0; i < 4; ++i)
    out[(size_t)(c0 + ty + 8*i) * R + r0 + tx] = (__bf16)t[tx][ty + 8*i];
}

// ------------------------------------------------- tiled bf16 transpose for V
// v: [b][s][h*128+d]  ->  vt: [b][h][d][s].  grid (SEQ/32, 128/32, NB*NH), block (32,8)
__global__ __launch_bounds__(256) void transpose_v(const __bf16* __restrict__ v,
                                                   __bf16* __restrict__ vt) {
  __shared__ __bf16 t[32][33];
  int b = blockIdx.z >> 4, h = blockIdx.z & 15;
  int s0 = blockIdx.x * 32, d0 = blockIdx.y * 32;
  int tx = threadIdx.x, ty = threadIdx.y;
#pragma unroll
  for (int i = 0; i < 4; ++i)
    t[ty + 8*i][tx] = v[(size_t)(b*SEQ + s0 + ty + 8*i) * 2048 + h*128 + d0 + tx];
  __syncthreads();
#pragma unroll
  for (int i = 0; i < 4; ++i)
    vt[((size_t)(b*NH + h) * 128 + d0 + ty + 8*i) * 2048 + s0 + tx] = t[tx][ty + 8*i];
}

// ------------------------------------------------- generic GEMM:  C[m][n] = sum_k A[m][k]*Bt[n][k]
// 128x128 tile, BK=32, 4 waves (2x2), each wave 64x64 = 4x4 mfma_16x16x32 frags
template <typename CT>
__global__ __launch_bounds__(256) void gemm_bt(const __bf16* __restrict__ A, int lda,
                                               const __bf16* __restrict__ Bt, int ldb,
                                               CT* __restrict__ C, int ldc, int K_) {
  __shared__ __align__(16) __bf16 As[128 * 32];
  __shared__ __align__(16) __bf16 Bs[128 * 32];
  const int m0 = blockIdx.y * 128, n0 = blockIdx.x * 128;
  const int t = threadIdx.x;
  const int wid = t >> 6, lane = t & 63;
  const int wr = (wid >> 1) * 64, wc = (wid & 1) * 64;
  const int lr = lane & 15, lg = lane >> 4;
  f32x4 acc[4][4] = {};
  for (int k0 = 0; k0 < K_; k0 += 32) {
    __syncthreads();
    {
      int o = t * 8;
      *(uint4*)(As + o) = *(const uint4*)(A + (size_t)(m0 + (o >> 5)) * lda + k0 + (o & 31));
      *(uint4*)(Bs + o) = *(const uint4*)(Bt + (size_t)(n0 + (o >> 5)) * ldb + k0 + (o & 31));
      int o2 = o + 2048;
      *(uint4*)(As + o2) = *(const uint4*)(A + (size_t)(m0 + (o2 >> 5)) * lda + k0 + (o2 & 31));
      *(uint4*)(Bs + o2) = *(const uint4*)(Bt + (size_t)(n0 + (o2 >> 5)) * ldb + k0 + (o2 & 31));
    }
    __syncthreads();
    bf16x8 af[4], bfr[4];
#pragma unroll
    for (int mi = 0; mi < 4; ++mi)
      af[mi] = *(const bf16x8*)(As + (wr + mi*16 + lr) * 32 + 8*lg);
#pragma unroll
    for (int ni = 0; ni < 4; ++ni)
      bfr[ni] = *(const bf16x8*)(Bs + (wc + ni*16 + lr) * 32 + 8*lg);
#pragma unroll
    for (int mi = 0; mi < 4; ++mi)
#pragma unroll
      for (int ni = 0; ni < 4; ++ni)
        acc[mi][ni] = __builtin_amdgcn_mfma_f32_16x16x32_bf16(af[mi], bfr[ni], acc[mi][ni], 0, 0, 0);
  }
#pragma unroll
  for (int mi = 0; mi < 4; ++mi)
#pragma unroll
    for (int ni = 0; ni < 4; ++ni) {
      int r = m0 + wr + mi*16 + lg*4;
      int c = n0 + wc + ni*16 + lr;
#pragma unroll
      for (int j = 0; j < 4; ++j)
        C[(size_t)(r + j) * ldc + c] = (CT)acc[mi][ni][j];
    }
}

// ------------------------------------------------- RoPE + concat-assemble
// nr: [bs][1024] (decoded no-rope part), rp: [bs][1024] (rope projection part)
// full: [bs][2048] laid out as (h,d) with d in [0,128); flat source index h*128+d:
//   <1024 -> nr, else rp.  RoPE applied to d in [64,128) per head.
// grid = ROWS*NH blocks, 64 threads
__global__ __launch_bounds__(64) void rope_assemble(const __bf16* __restrict__ nr,
                                                    const __bf16* __restrict__ rp,
                                                    __bf16* __restrict__ full) {
  int idx = blockIdx.x;
  int h = idx & 15, bs = idx >> 4;
  int s = bs & (SEQ - 1);
  int j = threadIdx.x;
  const size_t ibase = (size_t)bs * 1024;
  const size_t obase = (size_t)bs * 2048 + h * 128;
  auto get = [&](int d) -> float {
    int flat = h * 128 + d;
    return (flat < 1024) ? (float)nr[ibase + flat] : (float)rp[ibase + flat - 1024];
  };
  full[obase + j] = (__bf16)get(j);
  if (j < 32) {
    float t1 = get(64 + j), t2 = get(96 + j);
    // inv_freq = 10000^(-j/32) = 2^(-j*log2(10000)/32)
    float inv = exp2f(-0.41524101186092029f * (float)j);
    float ang = (float)s * inv;
    float sn, cs;
    sincosf(ang, &sn, &cs);
    full[obase + 64 + j] = (__bf16)(t1 * cs - t2 * sn);
    full[obase + 96 + j] = (__bf16)(t1 * sn + t2 * cs);
  }
}

// ------------------------------------------------- flash attention (1 wave, 16 q rows / block)
// qf,kf: [b][s][h*128+d] bf16; vt: [b][h][d][s] bf16; ctx out: [b][s][h*128+d] bf16
// grid (SEQ/16, NH, NB), block 64
__global__ __launch_bounds__(64) void attn_fwd(const __bf16* __restrict__ qf,
                                               const __bf16* __restrict__ kf,
                                               const __bf16* __restrict__ vt,
                                               __bf16* __restrict__ ctx) {
  const int q0 = blockIdx.x * 16;
  const int h = blockIdx.y, b = blockIdx.z;
  const int l = threadIdx.x, lr = l & 15, lg = l >> 4;
  __shared__ __align__(16) __bf16 P[16 * 40];  // [q][key 0..31], padded to 40
  bf16x8 qfr[4];
#pragma unroll
  for (int c = 0; c < 4; ++c)
    qfr[c] = *(const bf16x8*)(qf + (size_t)(b*SEQ + q0 + lr) * 2048 + h*128 + 32*c + 8*lg);
  f32x4 accO[8] = {};
  float m = -1e30f, lsum = 0.f;
  const float scale = 0.088388347648318447f;  // 1/sqrt(128)
  const __bf16* kbase = kf + (size_t)b * SEQ * 2048 + h * 128;
  const __bf16* vbase = vt + (size_t)(b*NH + h) * 128 * 2048;
  for (int kc = 0; kc < SEQ; kc += 32) {
    f32x4 s0 = {}, s1 = {};
#pragma unroll
    for (int c = 0; c < 4; ++c) {
      bf16x8 k0 = *(const bf16x8*)(kbase + (size_t)(kc + lr) * 2048 + 32*c + 8*lg);
      bf16x8 k1 = *(const bf16x8*)(kbase + (size_t)(kc + 16 + lr) * 2048 + 32*c + 8*lg);
      s0 = __builtin_amdgcn_mfma_f32_16x16x32_bf16(k0, qfr[c], s0, 0, 0, 0);
      s1 = __builtin_amdgcn_mfma_f32_16x16x32_bf16(k1, qfr[c], s1, 0, 0, 0);
    }
    // lane holds S^T for q = lr, keys kc + lg*4+j (s0) and kc+16+lg*4+j (s1)
    float sc[8];
#pragma unroll
    for (int j = 0; j < 4; ++j) { sc[j] = s0[j] * scale; sc[4 + j] = s1[j] * scale; }
    float cmax = sc[0];
#pragma unroll
    for (int j = 1; j < 8; ++j) cmax = fmaxf(cmax, sc[j]);
    cmax = fmaxf(cmax, __shfl_xor(cmax, 16));
    cmax = fmaxf(cmax, __shfl_xor(cmax, 32));
    float mnew = fmaxf(m, cmax);
    float corr = __expf(m - mnew);
    float p[8], psum = 0.f;
#pragma unroll
    for (int j = 0; j < 8; ++j) { p[j] = __expf(sc[j] - mnew); psum += p[j]; }
    psum += __shfl_xor(psum, 16);
    psum += __shfl_xor(psum, 32);
    lsum = lsum * corr + psum;
    m = mnew;
#pragma unroll
    for (int oc = 0; oc < 8; ++oc) accO[oc] *= corr;
    // bounce P to LDS to re-fragment for the PV mfma (B-operand layout)
#pragma unroll
    for (int j = 0; j < 4; ++j) {
      P[lr*40 + lg*4 + j]      = (__bf16)p[j];
      P[lr*40 + 16 + lg*4 + j] = (__bf16)p[4 + j];
    }
    __syncthreads();
    bf16x8 pf = *(const bf16x8*)(P + lr*40 + 8*lg);
#pragma unroll
    for (int oc = 0; oc < 8; ++oc) {
      bf16x8 vf = *(const bf16x8*)(vbase + (size_t)(oc*16 + lr) * 2048 + kc + 8*lg);
      accO[oc] = __builtin_amdgcn_mfma_f32_16x16x32_bf16(vf, pf, accO[oc], 0, 0, 0);
    }
    __syncthreads();
  }
  float inv = 1.f / lsum;
  size_t obase = (size_t)(b*SEQ + q0 + lr) * 2048 + h*128;
#pragma unroll
  for (int oc = 0; oc < 8; ++oc)
#pragma unroll
    for (int j = 0; j < 4; ++j)
      ctx[obase + oc*16 + lg*4 + j] = (__bf16)(accO[oc][j] * inv);
}

// ----------------------------------------------------------------------------
extern "C" void kernel_launch(void* const* d_in, const int* in_sizes, int n_in,
                              void* d_out, int out_size, void* d_ws, size_t ws_size,
                              hipStream_t stream) {
  const float* x   = (const float*)d_in[0];
  const float* Wc  = (const float*)d_in[1];
  const float* Wq  = (const float*)d_in[2];
  const float* Wk  = (const float*)d_in[3];
  const float* Wv  = (const float*)d_in[4];
  const float* Wrq = (const float*)d_in[5];
  const float* Wrk = (const float*)d_in[6];
  const float* Wo  = (const float*)d_in[7];
  float* out = (float*)d_out;

  char* ws = (char*)d_ws;
  size_t off = 0;
  auto take = [&](size_t bytes) { char* p = ws + off; off += bytes; return (__bf16*)p; };
  __bf16* xb    = take((size_t)ROWS * DM * 2);
  __bf16* comp  = take((size_t)ROWS * DL * 2);
  __bf16* qnr   = take((size_t)ROWS * 1024 * 2);
  __bf16* knr   = take((size_t)ROWS * 1024 * 2);
  __bf16* qr    = take((size_t)ROWS * 1024 * 2);
  __bf16* kr    = take((size_t)ROWS * 1024 * 2);
  __bf16* vb    = take((size_t)ROWS * 2048 * 2);
  __bf16* qfull = take((size_t)ROWS * 2048 * 2);
  __bf16* kfull = take((size_t)ROWS * 2048 * 2);
  __bf16* WcT   = take((size_t)512 * 2048 * 2);
  __bf16* WqT   = take((size_t)1024 * 256 * 2);
  __bf16* WkT   = take((size_t)1024 * 256 * 2);
  __bf16* WvT   = take((size_t)2048 * 256 * 2);
  __bf16* WrqT  = take((size_t)1024 * 2048 * 2);
  __bf16* WrkT  = take((size_t)1024 * 2048 * 2);
  __bf16* WoT   = take((size_t)2048 * 2048 * 2);
  __bf16* ctx = qnr;  // alias: qnr+knr dead after rope_assemble (16.8 MB)
  __bf16* vtr = qr;   // alias: qr+kr dead after rope_assemble (16.8 MB)

  dim3 tb(32, 8);
  cast_bf16<<<4096, 256, 0, stream>>>(x, xb, ROWS * DM / 4);
  transpose_cast<<<dim3(512/32,  2048/32), tb, 0, stream>>>(Wc,  WcT,  2048, 512);
  transpose_cast<<<dim3(1024/32, 256/32),  tb, 0, stream>>>(Wq,  WqT,  256, 1024);
  transpose_cast<<<dim3(1024/32, 256/32),  tb, 0, stream>>>(Wk,  WkT,  256, 1024);
  transpose_cast<<<dim3(2048/32, 256/32),  tb, 0, stream>>>(Wv,  WvT,  256, 2048);
  transpose_cast<<<dim3(1024/32, 2048/32), tb, 0, stream>>>(Wrq, WrqT, 2048, 1024);
  transpose_cast<<<dim3(1024/32, 2048/32), tb, 0, stream>>>(Wrk, WrkT, 2048, 1024);
  transpose_cast<<<dim3(2048/32, 2048/32), tb, 0, stream>>>(Wo,  WoT,  2048, 2048);

  // compressed = x @ W_comp  (bf16 out)
  gemm_bt<__bf16><<<dim3(512/128, ROWS/128), 256, 0, stream>>>(xb, DM, WcT, DM, comp, DL, DM);
  // q_rope / k_rope = x @ W_rope_{q,k}
  gemm_bt<__bf16><<<dim3(1024/128, ROWS/128), 256, 0, stream>>>(xb, DM, WrqT, DM, qr, 1024, DM);
  gemm_bt<__bf16><<<dim3(1024/128, ROWS/128), 256, 0, stream>>>(xb, DM, WrkT, DM, kr, 1024, DM);
  // q_no_rope / k_no_rope = c_qk @ W_{q,k}_dec ;  v = c_v @ W_v_dec
  gemm_bt<__bf16><<<dim3(1024/128, ROWS/128), 256, 0, stream>>>(comp, DL, WqT, 256, qnr, 1024, 256);
  gemm_bt<__bf16><<<dim3(1024/128, ROWS/128), 256, 0, stream>>>(comp, DL, WkT, 256, knr, 1024, 256);
  gemm_bt<__bf16><<<dim3(2048/128, ROWS/128), 256, 0, stream>>>(comp + 256, DL, WvT, 256, vb, 2048, 256);

  rope_assemble<<<ROWS * NH, 64, 0, stream>>>(qnr, qr, qfull);
  rope_assemble<<<ROWS * NH, 64, 0, stream>>>(knr, kr, kfull);
  transpose_v<<<dim3(SEQ/32, 128/32, NB*NH), tb, 0, stream>>>(vb, vtr);

  attn_fwd<<<dim3(SEQ/16, NH, NB), 64, 0, stream>>>(qfull, kfull, vtr, ctx);

  // out = ctx @ W_out  (f32 out)
  gemm_bt<float><<<dim3(2048/128, ROWS/128), 256, 0, stream>>>(ctx, DM, WoT, DM, out, 2048, DM);
}

// Round 2
// 740.403 us; speedup vs baseline: 1.2060x; 1.2060x over previous
//
#include <hip/hip_runtime.h>

typedef __bf16 bf16x8 __attribute__((ext_vector_type(8)));
typedef __bf16 bf16x4 __attribute__((ext_vector_type(4)));
typedef float f32x4 __attribute__((ext_vector_type(4)));

constexpr int NB   = 2;      // batch
constexpr int SEQ  = 2048;   // sequence
constexpr int DM   = 2048;   // d_model
constexpr int NH   = 16;     // heads
constexpr int HD   = 128;    // head dim
constexpr int DL   = 512;    // d_latent
constexpr int ROWS = NB * SEQ; // 4096

// ---------------------------------------------------------------- cast f32->bf16
__global__ __launch_bounds__(256) void cast_bf16(const float* __restrict__ in,
                                                 __bf16* __restrict__ out, int n4) {
  int i = blockIdx.x * blockDim.x + threadIdx.x;
  int stride = gridDim.x * blockDim.x;
  for (int k = i; k < n4; k += stride) {
    float4 v = ((const float4*)in)[k];
    union { __bf16 h[4]; uint2 u; } uo;
    uo.h[0] = (__bf16)v.x; uo.h[1] = (__bf16)v.y;
    uo.h[2] = (__bf16)v.z; uo.h[3] = (__bf16)v.w;
    ((uint2*)out)[k] = uo.u;
  }
}

// ------------------------------------------------- tiled transpose + cast f32->bf16
// out[c][r] = in[r][c];  grid (C/32, R/32), block (32,8)
__global__ __launch_bounds__(256) void transpose_cast(const float* __restrict__ in,
                                                      __bf16* __restrict__ out,
                                                      int R, int C) {
  __shared__ float t[32][33];
  int r0 = blockIdx.y * 32, c0 = blockIdx.x * 32;
  int tx = threadIdx.x, ty = threadIdx.y;
#pragma unroll
  for (int i = 0; i < 4; ++i)
    t[ty + 8*i][tx] = in[(size_t)(r0 + ty + 8*i) * C + c0 + tx];
  __syncthreads();
#pragma unroll
  for (int i = 0; i < 4; ++i)
    out[(size_t)(c0 + ty + 8*i) * R + r0 + tx] = (__bf16)t[tx][ty + 8*i];
}

// ------------------------------------------------- tiled bf16 transpose for V
// v: [b][s][h*128+d]  ->  vt: [b][h][d][s].  grid (SEQ/32, 128/32, NB*NH), block (32,8)
__global__ __launch_bounds__(256) void transpose_v(const __bf16* __restrict__ v,
                                                   __bf16* __restrict__ vt) {
  __shared__ __bf16 t[32][33];
  int b = blockIdx.z >> 4, h = blockIdx.z & 15;
  int s0 = blockIdx.x * 32, d0 = blockIdx.y * 32;
  int tx = threadIdx.x, ty = threadIdx.y;
#pragma unroll
  for (int i = 0; i < 4; ++i)
    t[ty + 8*i][tx] = v[(size_t)(b*SEQ + s0 + ty + 8*i) * 2048 + h*128 + d0 + tx];
  __syncthreads();
#pragma unroll
  for (int i = 0; i < 4; ++i)
    vt[((size_t)(b*NH + h) * 128 + d0 + ty + 8*i) * 2048 + s0 + tx] = t[tx][ty + 8*i];
}

// ------------------------------------------------- generic GEMM:  C[m][n] = sum_k A[m][k]*Bt[n][k]
// 128x128 tile, BK=32, 4 waves (2x2), each wave 64x64 = 4x4 mfma_16x16x32 frags
template <typename CT>
__global__ __launch_bounds__(256) void gemm_bt(const __bf16* __restrict__ A, int lda,
                                               const __bf16* __restrict__ Bt, int ldb,
                                               CT* __restrict__ C, int ldc, int K_) {
  __shared__ __align__(16) __bf16 As[128 * 32];
  __shared__ __align__(16) __bf16 Bs[128 * 32];
  const int m0 = blockIdx.y * 128, n0 = blockIdx.x * 128;
  const int t = threadIdx.x;
  const int wid = t >> 6, lane = t & 63;
  const int wr = (wid >> 1) * 64, wc = (wid & 1) * 64;
  const int lr = lane & 15, lg = lane >> 4;
  f32x4 acc[4][4] = {};
  for (int k0 = 0; k0 < K_; k0 += 32) {
    __syncthreads();
    {
      int o = t * 8;
      *(uint4*)(As + o) = *(const uint4*)(A + (size_t)(m0 + (o >> 5)) * lda + k0 + (o & 31));
      *(uint4*)(Bs + o) = *(const uint4*)(Bt + (size_t)(n0 + (o >> 5)) * ldb + k0 + (o & 31));
      int o2 = o + 2048;
      *(uint4*)(As + o2) = *(const uint4*)(A + (size_t)(m0 + (o2 >> 5)) * lda + k0 + (o2 & 31));
      *(uint4*)(Bs + o2) = *(const uint4*)(Bt + (size_t)(n0 + (o2 >> 5)) * ldb + k0 + (o2 & 31));
    }
    __syncthreads();
    bf16x8 af[4], bfr[4];
#pragma unroll
    for (int mi = 0; mi < 4; ++mi)
      af[mi] = *(const bf16x8*)(As + (wr + mi*16 + lr) * 32 + 8*lg);
#pragma unroll
    for (int ni = 0; ni < 4; ++ni)
      bfr[ni] = *(const bf16x8*)(Bs + (wc + ni*16 + lr) * 32 + 8*lg);
#pragma unroll
    for (int mi = 0; mi < 4; ++mi)
#pragma unroll
      for (int ni = 0; ni < 4; ++ni)
        acc[mi][ni] = __builtin_amdgcn_mfma_f32_16x16x32_bf16(af[mi], bfr[ni], acc[mi][ni], 0, 0, 0);
  }
#pragma unroll
  for (int mi = 0; mi < 4; ++mi)
#pragma unroll
    for (int ni = 0; ni < 4; ++ni) {
      int r = m0 + wr + mi*16 + lg*4;
      int c = n0 + wc + ni*16 + lr;
#pragma unroll
      for (int j = 0; j < 4; ++j)
        C[(size_t)(r + j) * ldc + c] = (CT)acc[mi][ni][j];
    }
}

// ------------------------------------------------- RoPE + concat-assemble
__global__ __launch_bounds__(64) void rope_assemble(const __bf16* __restrict__ nr,
                                                    const __bf16* __restrict__ rp,
                                                    __bf16* __restrict__ full) {
  int idx = blockIdx.x;
  int h = idx & 15, bs = idx >> 4;
  int s = bs & (SEQ - 1);
  int j = threadIdx.x;
  const size_t ibase = (size_t)bs * 1024;
  const size_t obase = (size_t)bs * 2048 + h * 128;
  auto get = [&](int d) -> float {
    int flat = h * 128 + d;
    return (flat < 1024) ? (float)nr[ibase + flat] : (float)rp[ibase + flat - 1024];
  };
  full[obase + j] = (__bf16)get(j);
  if (j < 32) {
    float t1 = get(64 + j), t2 = get(96 + j);
    float inv = exp2f(-0.41524101186092029f * (float)j);
    float ang = (float)s * inv;
    float sn, cs;
    sincosf(ang, &sn, &cs);
    full[obase + 64 + j] = (__bf16)(t1 * cs - t2 * sn);
    full[obase + 96 + j] = (__bf16)(t1 * sn + t2 * cs);
  }
}

// ------------------------------------------------- flash attention v2
// 4 waves / block; wave w owns q rows [q0 + w*16, +16). V^T staged in LDS
// (shared by the 4 waves, reg-prefetched); K frags global->reg (L2); P bounce
// in per-wave LDS slices (no barrier needed). 2 barriers per 32-key chunk.
// qf,kf: [b][s][h*128+d] bf16; vt: [b][h][d][s] bf16; ctx out: [b][s][h*128+d]
// grid (SEQ/64, NH, NB), block 256
__global__ __launch_bounds__(256) void attn_fwd(const __bf16* __restrict__ qf,
                                                const __bf16* __restrict__ kf,
                                                const __bf16* __restrict__ vt,
                                                __bf16* __restrict__ ctx) {
  __shared__ __align__(16) __bf16 Vs[128][40];    // [d][key], pad 40 (~2-way, free)
  __shared__ __align__(16) __bf16 Ps[4][16][40];  // per-wave [q][key]
  const int t = threadIdx.x;
  const int wid = t >> 6, lane = t & 63;
  const int lr = lane & 15, lg = lane >> 4;
  const int h = blockIdx.y, b = blockIdx.z;
  const int q0 = blockIdx.x * 64 + wid * 16;
  const __bf16* kbase = kf + (size_t)b * SEQ * 2048 + h * 128;
  const __bf16* vbase = vt + (size_t)(b*NH + h) * 128 * 2048;

  // per-thread V-stage mapping: vector idx vi = t + 256*i (i<2) -> d = vi>>2, col = (vi&3)*8
  const int vd0 = t >> 2, vc0 = (t & 3) * 8;

  bf16x8 qfr[4];
#pragma unroll
  for (int c = 0; c < 4; ++c)
    qfr[c] = *(const bf16x8*)(qf + (size_t)(b*SEQ + q0 + lr) * 2048 + h*128 + 32*c + 8*lg);

  f32x4 accO[8] = {};
  float m = -1e30f, lsum = 0.f;
  const float scale = 0.088388347648318447f;  // 1/sqrt(128)

  bf16x8 pv[2];
#pragma unroll
  for (int i = 0; i < 2; ++i)
    pv[i] = *(const bf16x8*)(vbase + (size_t)(vd0 + 64*i) * 2048 + vc0);

  for (int kc = 0; kc < SEQ; kc += 32) {
    // write prefetched V tile to LDS (prev chunk's readers done per loop-end barrier)
#pragma unroll
    for (int i = 0; i < 2; ++i)
      *(bf16x8*)(&Vs[vd0 + 64*i][vc0]) = pv[i];
    // issue this chunk's K fragment loads; latency hides under the barrier wait
    bf16x8 kfr[8];
#pragma unroll
    for (int t4 = 0; t4 < 2; ++t4)
#pragma unroll
      for (int c = 0; c < 4; ++c)
        kfr[t4*4 + c] = *(const bf16x8*)(kbase + (size_t)(kc + 16*t4 + lr) * 2048 + 32*c + 8*lg);
    __syncthreads();
    // prefetch next V tile (in flight across compute; drained by loop-end barrier)
    if (kc + 32 < SEQ) {
#pragma unroll
      for (int i = 0; i < 2; ++i)
        pv[i] = *(const bf16x8*)(vbase + (size_t)(vd0 + 64*i) * 2048 + (kc + 32) + vc0);
    }
    // QK^T (S^T): lane holds scores for q = q0+lr, keys kc + 16*t4 + 4*lg + j
    f32x4 s4[2] = {};
#pragma unroll
    for (int t4 = 0; t4 < 2; ++t4)
#pragma unroll
      for (int c = 0; c < 4; ++c)
        s4[t4] = __builtin_amdgcn_mfma_f32_16x16x32_bf16(kfr[t4*4 + c], qfr[c], s4[t4], 0, 0, 0);
    float sc[8];
#pragma unroll
    for (int j = 0; j < 4; ++j) { sc[j] = s4[0][j] * scale; sc[4 + j] = s4[1][j] * scale; }
    float cmax = sc[0];
#pragma unroll
    for (int j = 1; j < 8; ++j) cmax = fmaxf(cmax, sc[j]);
    cmax = fmaxf(cmax, __shfl_xor(cmax, 16));
    cmax = fmaxf(cmax, __shfl_xor(cmax, 32));
    float mnew = fmaxf(m, cmax);
    float corr = __expf(m - mnew);
    float p[8], psum = 0.f;
#pragma unroll
    for (int j = 0; j < 8; ++j) { p[j] = __expf(sc[j] - mnew); psum += p[j]; }
    psum += __shfl_xor(psum, 16);
    psum += __shfl_xor(psum, 32);
    lsum = lsum * corr + psum;
    m = mnew;
#pragma unroll
    for (int oc = 0; oc < 8; ++oc) accO[oc] *= corr;
    // P -> per-wave LDS slice (same-wave RAW ordered by lgkmcnt; no barrier)
#pragma unroll
    for (int t4 = 0; t4 < 2; ++t4) {
      bf16x4 pw;
#pragma unroll
      for (int j = 0; j < 4; ++j) pw[j] = (__bf16)p[t4*4 + j];
      *(bf16x4*)(&Ps[wid][lr][16*t4 + 4*lg]) = pw;
    }
    bf16x8 pfr = *(const bf16x8*)(&Ps[wid][lr][8*lg]);
    // PV: accO[oc] += V^T[d, keys] * P
#pragma unroll
    for (int oc = 0; oc < 8; ++oc) {
      bf16x8 vf = *(const bf16x8*)(&Vs[oc*16 + lr][8*lg]);
      accO[oc] = __builtin_amdgcn_mfma_f32_16x16x32_bf16(vf, pfr, accO[oc], 0, 0, 0);
    }
    __syncthreads();
  }
  float inv = 1.f / lsum;
  size_t obase = (size_t)(b*SEQ + q0 + lr) * 2048 + h*128;
#pragma unroll
  for (int oc = 0; oc < 8; ++oc)
#pragma unroll
    for (int j = 0; j < 4; ++j)
      ctx[obase + oc*16 + lg*4 + j] = (__bf16)(accO[oc][j] * inv);
}

// ----------------------------------------------------------------------------
extern "C" void kernel_launch(void* const* d_in, const int* in_sizes, int n_in,
                              void* d_out, int out_size, void* d_ws, size_t ws_size,
                              hipStream_t stream) {
  const float* x   = (const float*)d_in[0];
  const float* Wc  = (const float*)d_in[1];
  const float* Wq  = (const float*)d_in[2];
  const float* Wk  = (const float*)d_in[3];
  const float* Wv  = (const float*)d_in[4];
  const float* Wrq = (const float*)d_in[5];
  const float* Wrk = (const float*)d_in[6];
  const float* Wo  = (const float*)d_in[7];
  float* out = (float*)d_out;

  char* ws = (char*)d_ws;
  size_t off = 0;
  auto take = [&](size_t bytes) { char* p = ws + off; off += bytes; return (__bf16*)p; };
  __bf16* xb    = take((size_t)ROWS * DM * 2);
  __bf16* comp  = take((size_t)ROWS * DL * 2);
  __bf16* qnr   = take((size_t)ROWS * 1024 * 2);
  __bf16* knr   = take((size_t)ROWS * 1024 * 2);
  __bf16* qr    = take((size_t)ROWS * 1024 * 2);
  __bf16* kr    = take((size_t)ROWS * 1024 * 2);
  __bf16* vb    = take((size_t)ROWS * 2048 * 2);
  __bf16* qfull = take((size_t)ROWS * 2048 * 2);
  __bf16* kfull = take((size_t)ROWS * 2048 * 2);
  __bf16* WcT   = take((size_t)512 * 2048 * 2);
  __bf16* WqT   = take((size_t)1024 * 256 * 2);
  __bf16* WkT   = take((size_t)1024 * 256 * 2);
  __bf16* WvT   = take((size_t)2048 * 256 * 2);
  __bf16* WrqT  = take((size_t)1024 * 2048 * 2);
  __bf16* WrkT  = take((size_t)1024 * 2048 * 2);
  __bf16* WoT   = take((size_t)2048 * 2048 * 2);
  __bf16* ctx = qnr;  // alias: qnr+knr dead after rope_assemble (16.8 MB)
  __bf16* vtr = qr;   // alias: qr+kr dead after rope_assemble (16.8 MB)

  dim3 tb(32, 8);
  cast_bf16<<<4096, 256, 0, stream>>>(x, xb, ROWS * DM / 4);
  transpose_cast<<<dim3(512/32,  2048/32), tb, 0, stream>>>(Wc,  WcT,  2048, 512);
  transpose_cast<<<dim3(1024/32, 256/32),  tb, 0, stream>>>(Wq,  WqT,  256, 1024);
  transpose_cast<<<dim3(1024/32, 256/32),  tb, 0, stream>>>(Wk,  WkT,  256, 1024);
  transpose_cast<<<dim3(2048/32, 256/32),  tb, 0, stream>>>(Wv,  WvT,  256, 2048);
  transpose_cast<<<dim3(1024/32, 2048/32), tb, 0, stream>>>(Wrq, WrqT, 2048, 1024);
  transpose_cast<<<dim3(1024/32, 2048/32), tb, 0, stream>>>(Wrk, WrkT, 2048, 1024);
  transpose_cast<<<dim3(2048/32, 2048/32), tb, 0, stream>>>(Wo,  WoT,  2048, 2048);

  gemm_bt<__bf16><<<dim3(512/128, ROWS/128), 256, 0, stream>>>(xb, DM, WcT, DM, comp, DL, DM);
  gemm_bt<__bf16><<<dim3(1024/128, ROWS/128), 256, 0, stream>>>(xb, DM, WrqT, DM, qr, 1024, DM);
  gemm_bt<__bf16><<<dim3(1024/128, ROWS/128), 256, 0, stream>>>(xb, DM, WrkT, DM, kr, 1024, DM);
  gemm_bt<__bf16><<<dim3(1024/128, ROWS/128), 256, 0, stream>>>(comp, DL, WqT, 256, qnr, 1024, 256);
  gemm_bt<__bf16><<<dim3(1024/128, ROWS/128), 256, 0, stream>>>(comp, DL, WkT, 256, knr, 1024, 256);
  gemm_bt<__bf16><<<dim3(2048/128, ROWS/128), 256, 0, stream>>>(comp + 256, DL, WvT, 256, vb, 2048, 256);

  rope_assemble<<<ROWS * NH, 64, 0, stream>>>(qnr, qr, qfull);
  rope_assemble<<<ROWS * NH, 64, 0, stream>>>(knr, kr, kfull);
  transpose_v<<<dim3(SEQ/32, 128/32, NB*NH), tb, 0, stream>>>(vb, vtr);

  attn_fwd<<<dim3(SEQ/64, NH, NB), 256, 0, stream>>>(qfull, kfull, vtr, ctx);

  gemm_bt<float><<<dim3(2048/128, ROWS/128), 256, 0, stream>>>(ctx, DM, WoT, DM, out, 2048, DM);
}

// Round 3
// 500.225 us; speedup vs baseline: 1.7851x; 1.4801x over previous
//
#include <hip/hip_runtime.h>
#include <stdint.h>

typedef __bf16 bf16x8 __attribute__((ext_vector_type(8)));
typedef __bf16 bf16x4 __attribute__((ext_vector_type(4)));
typedef float f32x4 __attribute__((ext_vector_type(4)));
typedef float f32x16 __attribute__((ext_vector_type(16)));

constexpr int NB   = 2;      // batch
constexpr int SEQ  = 2048;   // sequence
constexpr int DM   = 2048;   // d_model
constexpr int NH   = 16;     // heads
constexpr int HD   = 128;    // head dim
constexpr int DL   = 512;    // d_latent
constexpr int ROWS = NB * SEQ; // 4096

// async global->LDS, 16B per lane; LDS dest = wave-uniform base + lane*16
__device__ __forceinline__ void gload16(const void* g, void* l) {
  __builtin_amdgcn_global_load_lds((const __attribute__((address_space(1))) uint32_t*)(const void*)g,
                                   (__attribute__((address_space(3))) uint32_t*)(void*)l, 16, 0, 0);
}

__device__ __forceinline__ uint32_t pk2(float lo, float hi) {
  union { __bf16 h[2]; uint32_t u; } x;
  x.h[0] = (__bf16)lo; x.h[1] = (__bf16)hi;
  return x.u;
}

// ---------------------------------------------------------------- cast f32->bf16
__global__ __launch_bounds__(256) void cast_bf16(const float* __restrict__ in,
                                                 __bf16* __restrict__ out, int n4) {
  int i = blockIdx.x * blockDim.x + threadIdx.x;
  int stride = gridDim.x * blockDim.x;
  for (int k = i; k < n4; k += stride) {
    float4 v = ((const float4*)in)[k];
    union { __bf16 h[4]; uint2 u; } uo;
    uo.h[0] = (__bf16)v.x; uo.h[1] = (__bf16)v.y;
    uo.h[2] = (__bf16)v.z; uo.h[3] = (__bf16)v.w;
    ((uint2*)out)[k] = uo.u;
  }
}

// ------------------------------------------------- tiled transpose + cast f32->bf16
__global__ __launch_bounds__(256) void transpose_cast(const float* __restrict__ in,
                                                      __bf16* __restrict__ out,
                                                      int R, int C) {
  __shared__ float t[32][33];
  int r0 = blockIdx.y * 32, c0 = blockIdx.x * 32;
  int tx = threadIdx.x, ty = threadIdx.y;
#pragma unroll
  for (int i = 0; i < 4; ++i)
    t[ty + 8*i][tx] = in[(size_t)(r0 + ty + 8*i) * C + c0 + tx];
  __syncthreads();
#pragma unroll
  for (int i = 0; i < 4; ++i)
    out[(size_t)(c0 + ty + 8*i) * R + r0 + tx] = (__bf16)t[tx][ty + 8*i];
}

// ------------------------------------------------- tiled bf16 transpose for V
// v: [b][s][h*128+d] -> vt: [b][h][d][s]
__global__ __launch_bounds__(256) void transpose_v(const __bf16* __restrict__ v,
                                                   __bf16* __restrict__ vt) {
  __shared__ __bf16 t[32][33];
  int b = blockIdx.z >> 4, h = blockIdx.z & 15;
  int s0 = blockIdx.x * 32, d0 = blockIdx.y * 32;
  int tx = threadIdx.x, ty = threadIdx.y;
#pragma unroll
  for (int i = 0; i < 4; ++i)
    t[ty + 8*i][tx] = v[(size_t)(b*SEQ + s0 + ty + 8*i) * 2048 + h*128 + d0 + tx];
  __syncthreads();
#pragma unroll
  for (int i = 0; i < 4; ++i)
    vt[((size_t)(b*NH + h) * 128 + d0 + ty + 8*i) * 2048 + s0 + tx] = t[tx][ty + 8*i];
}

// ------------------------------------------------- generic GEMM:  C[m][n] = sum_k A[m][k]*Bt[n][k]
// 128x128 tile, BK=32, 4 waves, global_load_lds (width 16) staging (m97 pattern)
template <typename CT>
__global__ __launch_bounds__(256) void gemm_bt(const __bf16* __restrict__ A, int lda,
                                               const __bf16* __restrict__ Bt, int ldb,
                                               CT* __restrict__ C, int ldc, int K_) {
  __shared__ __align__(16) __bf16 As[128 * 32];
  __shared__ __align__(16) __bf16 Bs[128 * 32];
  const int m0 = blockIdx.y * 128, n0 = blockIdx.x * 128;
  const int t = threadIdx.x;
  const int wid = t >> 6, lane = t & 63;
  const int wr = (wid >> 1) * 64, wc = (wid & 1) * 64;
  const int lr = lane & 15, lg = lane >> 4;
  f32x4 acc[4][4] = {};
  for (int k0 = 0; k0 < K_; k0 += 32) {
    __syncthreads();  // readers of previous tile done
#pragma unroll
    for (int j = 0; j < 2; ++j) {
      int ob = j * 4096 + wid * 1024;   // wave-uniform LDS byte base
      int o  = ob + lane * 16;          // this lane's linear byte target
      int row = o >> 6, colb = o & 63;  // 64B rows (32 bf16)
      gload16((const char*)A  + ((size_t)(m0 + row) * lda + k0) * 2 + colb, (char*)As + ob);
      gload16((const char*)Bt + ((size_t)(n0 + row) * ldb + k0) * 2 + colb, (char*)Bs + ob);
    }
    __syncthreads();  // drains vmcnt -> staging complete
    bf16x8 af[4], bfr[4];
#pragma unroll
    for (int mi = 0; mi < 4; ++mi)
      af[mi] = *(const bf16x8*)(As + (wr + mi*16 + lr) * 32 + 8*lg);
#pragma unroll
    for (int ni = 0; ni < 4; ++ni)
      bfr[ni] = *(const bf16x8*)(Bs + (wc + ni*16 + lr) * 32 + 8*lg);
#pragma unroll
    for (int mi = 0; mi < 4; ++mi)
#pragma unroll
      for (int ni = 0; ni < 4; ++ni)
        acc[mi][ni] = __builtin_amdgcn_mfma_f32_16x16x32_bf16(af[mi], bfr[ni], acc[mi][ni], 0, 0, 0);
  }
#pragma unroll
  for (int mi = 0; mi < 4; ++mi)
#pragma unroll
    for (int ni = 0; ni < 4; ++ni) {
      int r = m0 + wr + mi*16 + lg*4;
      int c = n0 + wc + ni*16 + lr;
#pragma unroll
      for (int j = 0; j < 4; ++j)
        C[(size_t)(r + j) * ldc + c] = (CT)acc[mi][ni][j];
    }
}

// ------------------------------------------------- RoPE + concat-assemble
__global__ __launch_bounds__(64) void rope_assemble(const __bf16* __restrict__ nr,
                                                    const __bf16* __restrict__ rp,
                                                    __bf16* __restrict__ full) {
  int idx = blockIdx.x;
  int h = idx & 15, bs = idx >> 4;
  int s = bs & (SEQ - 1);
  int j = threadIdx.x;
  const size_t ibase = (size_t)bs * 1024;
  const size_t obase = (size_t)bs * 2048 + h * 128;
  auto get = [&](int d) -> float {
    int flat = h * 128 + d;
    return (flat < 1024) ? (float)nr[ibase + flat] : (float)rp[ibase + flat - 1024];
  };
  full[obase + j] = (__bf16)get(j);
  if (j < 32) {
    float t1 = get(64 + j), t2 = get(96 + j);
    float inv = exp2f(-0.41524101186092029f * (float)j);
    float ang = (float)s * inv;
    float sn, cs;
    sincosf(ang, &sn, &cs);
    full[obase + 64 + j] = (__bf16)(t1 * cs - t2 * sn);
    full[obase + 96 + j] = (__bf16)(t1 * sn + t2 * cs);
  }
}

// ------------------------------------------------- flash attention v3 (32x32 swapped-QK^T)
// 4 waves/block, 32 q-rows/wave, KVBLK=64. K,V^T double-buffered in LDS with
// XOR-swizzle (byte ^= (row&7)<<4), staged via global_load_lds from
// inverse-swizzled global addresses. One barrier per 64-key step.
// S^T = mfma(K,Q): lane holds 16 of 32 keys for q=lane&31 (partner lane^32 has rest).
// grid (SEQ/128, NH, NB), block 256
__global__ __launch_bounds__(256, 2) void attn_fwd(const __bf16* __restrict__ qf,
                                                   const __bf16* __restrict__ kf,
                                                   const __bf16* __restrict__ vt,
                                                   __bf16* __restrict__ ctx) {
  __shared__ __align__(16) char Ks[2][16384];  // [key 0..63][d 0..127] swizzled, 256B rows
  __shared__ __align__(16) char Vs[2][16384];  // [d 0..127][key 0..63] swizzled, 128B rows
  const int t = threadIdx.x;
  const int wid = t >> 6, lane = t & 63;
  const int lq = lane & 31, hi = lane >> 5;
  const int h = blockIdx.y, b = blockIdx.z;
  const int qrow = blockIdx.x * 128 + wid * 32 + lq;
  const char* kbh = (const char*)(kf + (size_t)b * SEQ * DM + h * HD);
  const char* vbh = (const char*)(vt + (size_t)(b * NH + h) * HD * SEQ);

  // Q fragments (B-operand): qfr[kk] holds Q[qrow][16*kk + 8*hi .. +8]
  bf16x8 qfr[8];
  const __bf16* qrp = qf + (size_t)(b * SEQ + qrow) * DM + h * HD;
#pragma unroll
  for (int kk = 0; kk < 8; ++kk)
    qfr[kk] = *(const bf16x8*)(qrp + kk * 16 + 8 * hi);

  f32x16 accO[4] = {};   // O^T[dblk*32 + rowmap][q]
  float mrun = -1e30f, lsum = 0.f;
  const float scale = 0.088388347648318447f;  // 1/sqrt(128)

  auto stageK = [&](int buf, int kc) {
#pragma unroll
    for (int i = 0; i < 4; ++i) {
      int ob = wid * 4096 + i * 1024;       // wave-uniform
      int o  = ob + lane * 16;              // linear LDS byte this lane fills
      int key = o >> 8, sb = o & 255;
      int cb  = sb ^ ((key & 7) << 4);      // inverse swizzle on the SOURCE
      gload16(kbh + (size_t)(kc + key) * (DM * 2) + cb, Ks[buf] + ob);
    }
  };
  auto stageV = [&](int buf, int kc) {
#pragma unroll
    for (int i = 0; i < 4; ++i) {
      int ob = wid * 4096 + i * 1024;
      int o  = ob + lane * 16;
      int d = o >> 7, sb = o & 127;
      int cb = sb ^ ((d & 7) << 4);
      gload16(vbh + (size_t)d * (SEQ * 2) + (size_t)kc * 2 + cb, Vs[buf] + ob);
    }
  };

  stageK(0, 0); stageV(0, 0);
  __syncthreads();  // drains vmcnt -> tile 0 ready
  int cur = 0;
  for (int kc = 0; kc < SEQ; kc += 64) {
    if (kc + 64 < SEQ) { stageK(cur ^ 1, kc + 64); stageV(cur ^ 1, kc + 64); }

    // ---- QK^T: st[tt] = S^T for keys kc+32*tt+..., q = qrow
    f32x16 st[2] = {};
#pragma unroll
    for (int tt = 0; tt < 2; ++tt) {
      const int key = tt * 32 + lq;
      const char* kb = Ks[cur] + key * 256;
      const int swz = (key & 7) << 4;
#pragma unroll
      for (int kk = 0; kk < 8; ++kk) {
        bf16x8 kfr = *(const bf16x8*)(kb + ((32 * kk + 16 * hi) ^ swz));
        st[tt] = __builtin_amdgcn_mfma_f32_32x32x16_bf16(kfr, qfr[kk], st[tt], 0, 0, 0);
      }
    }

    // ---- online softmax (keys split lane/lane^32)
    float p[2][16];
    float cmax = -1e30f;
#pragma unroll
    for (int tt = 0; tt < 2; ++tt)
#pragma unroll
      for (int r = 0; r < 16; ++r) {
        float v = st[tt][r] * scale;
        p[tt][r] = v;
        cmax = fmaxf(cmax, v);
      }
    cmax = fmaxf(cmax, __shfl_xor(cmax, 32));
    float mnew = fmaxf(mrun, cmax);
    float corr = __expf(mrun - mnew);
    float psum = 0.f;
#pragma unroll
    for (int tt = 0; tt < 2; ++tt)
#pragma unroll
      for (int r = 0; r < 16; ++r) {
        p[tt][r] = __expf(p[tt][r] - mnew);
        psum += p[tt][r];
      }
    psum += __shfl_xor(psum, 32);
    lsum = lsum * corr + psum;
    mrun = mnew;
#pragma unroll
    for (int db = 0; db < 4; ++db) accO[db] *= corr;

    // ---- build P B-frags in-register (key slice sl: keys kc+16*sl+8*hi+i)
    // lane reg r of tile tt holds key 32*tt + (r&3) + 8*(r>>2) + 4*hi.
    // lo reader frag = [own a-pack | partner a-pack]; hi = [partner b-pack | own b-pack]
    bf16x8 pfrag[4];
#pragma unroll
    for (int sl = 0; sl < 4; ++sl) {
      const int tt = sl >> 1, kk = sl & 1;
      uint32_t a0 = pk2(p[tt][8*kk + 0], p[tt][8*kk + 1]);
      uint32_t a1 = pk2(p[tt][8*kk + 2], p[tt][8*kk + 3]);
      uint32_t b0 = pk2(p[tt][8*kk + 4], p[tt][8*kk + 5]);
      uint32_t b1 = pk2(p[tt][8*kk + 6], p[tt][8*kk + 7]);
      uint32_t pa0 = (uint32_t)__shfl_xor((int)a0, 32);
      uint32_t pa1 = (uint32_t)__shfl_xor((int)a1, 32);
      uint32_t pb0 = (uint32_t)__shfl_xor((int)b0, 32);
      uint32_t pb1 = (uint32_t)__shfl_xor((int)b1, 32);
      union { uint32_t u[4]; bf16x8 v; } pu;
      pu.u[0] = hi ? pb0 : a0;
      pu.u[1] = hi ? pb1 : a1;
      pu.u[2] = hi ? b0 : pa0;
      pu.u[3] = hi ? b1 : pa1;
      pfrag[sl] = pu.v;
    }

    // ---- PV: accO[db] += V^T[32*db + lq][key slice] * P
#pragma unroll
    for (int db = 0; db < 4; ++db) {
      const int d = db * 32 + lq;
      const char* vb = Vs[cur] + d * 128;
      const int swz = (d & 7) << 4;
#pragma unroll
      for (int sl = 0; sl < 4; ++sl) {
        bf16x8 vfr = *(const bf16x8*)(vb + ((32 * sl + 16 * hi) ^ swz));
        accO[db] = __builtin_amdgcn_mfma_f32_32x32x16_bf16(vfr, pfrag[sl], accO[db], 0, 0, 0);
      }
    }
    __syncthreads();  // drains vmcnt (next tile staged) + all waves done reading cur
    cur ^= 1;
  }

  // ---- epilogue: O[q][d] = accO / lsum ; reg 4a+j -> d = 32*db + 8*a + 4*hi + j
  float inv = 1.f / lsum;
  __bf16* op = ctx + (size_t)(b * SEQ + qrow) * DM + h * HD;
#pragma unroll
  for (int db = 0; db < 4; ++db)
#pragma unroll
    for (int a = 0; a < 4; ++a) {
      bf16x4 o4;
#pragma unroll
      for (int j = 0; j < 4; ++j) o4[j] = (__bf16)(accO[db][4*a + j] * inv);
      *(bf16x4*)(op + db*32 + 8*a + 4*hi) = o4;
    }
}

// ----------------------------------------------------------------------------
extern "C" void kernel_launch(void* const* d_in, const int* in_sizes, int n_in,
                              void* d_out, int out_size, void* d_ws, size_t ws_size,
                              hipStream_t stream) {
  const float* x   = (const float*)d_in[0];
  const float* Wc  = (const float*)d_in[1];
  const float* Wq  = (const float*)d_in[2];
  const float* Wk  = (const float*)d_in[3];
  const float* Wv  = (const float*)d_in[4];
  const float* Wrq = (const float*)d_in[5];
  const float* Wrk = (const float*)d_in[6];
  const float* Wo  = (const float*)d_in[7];
  float* out = (float*)d_out;

  char* ws = (char*)d_ws;
  size_t off = 0;
  auto take = [&](size_t bytes) { char* p = ws + off; off += bytes; return (__bf16*)p; };
  __bf16* xb    = take((size_t)ROWS * DM * 2);
  __bf16* comp  = take((size_t)ROWS * DL * 2);
  __bf16* qnr   = take((size_t)ROWS * 1024 * 2);
  __bf16* knr   = take((size_t)ROWS * 1024 * 2);
  __bf16* qr    = take((size_t)ROWS * 1024 * 2);
  __bf16* kr    = take((size_t)ROWS * 1024 * 2);
  __bf16* vb    = take((size_t)ROWS * 2048 * 2);
  __bf16* qfull = take((size_t)ROWS * 2048 * 2);
  __bf16* kfull = take((size_t)ROWS * 2048 * 2);
  __bf16* WcT   = take((size_t)512 * 2048 * 2);
  __bf16* WqT   = take((size_t)1024 * 256 * 2);
  __bf16* WkT   = take((size_t)1024 * 256 * 2);
  __bf16* WvT   = take((size_t)2048 * 256 * 2);
  __bf16* WrqT  = take((size_t)1024 * 2048 * 2);
  __bf16* WrkT  = take((size_t)1024 * 2048 * 2);
  __bf16* WoT   = take((size_t)2048 * 2048 * 2);
  __bf16* ctx = qnr;  // alias: qnr+knr dead after rope_assemble
  __bf16* vtr = qr;   // alias: qr+kr dead after rope_assemble

  dim3 tb(32, 8);
  cast_bf16<<<4096, 256, 0, stream>>>(x, xb, ROWS * DM / 4);
  transpose_cast<<<dim3(512/32,  2048/32), tb, 0, stream>>>(Wc,  WcT,  2048, 512);
  transpose_cast<<<dim3(1024/32, 256/32),  tb, 0, stream>>>(Wq,  WqT,  256, 1024);
  transpose_cast<<<dim3(1024/32, 256/32),  tb, 0, stream>>>(Wk,  WkT,  256, 1024);
  transpose_cast<<<dim3(2048/32, 256/32),  tb, 0, stream>>>(Wv,  WvT,  256, 2048);
  transpose_cast<<<dim3(1024/32, 2048/32), tb, 0, stream>>>(Wrq, WrqT, 2048, 1024);
  transpose_cast<<<dim3(1024/32, 2048/32), tb, 0, stream>>>(Wrk, WrkT, 2048, 1024);
  transpose_cast<<<dim3(2048/32, 2048/32), tb, 0, stream>>>(Wo,  WoT,  2048, 2048);

  gemm_bt<__bf16><<<dim3(512/128, ROWS/128), 256, 0, stream>>>(xb, DM, WcT, DM, comp, DL, DM);
  gemm_bt<__bf16><<<dim3(1024/128, ROWS/128), 256, 0, stream>>>(xb, DM, WrqT, DM, qr, 1024, DM);
  gemm_bt<__bf16><<<dim3(1024/128, ROWS/128), 256, 0, stream>>>(xb, DM, WrkT, DM, kr, 1024, DM);
  gemm_bt<__bf16><<<dim3(1024/128, ROWS/128), 256, 0, stream>>>(comp, DL, WqT, 256, qnr, 1024, 256);
  gemm_bt<__bf16><<<dim3(1024/128, ROWS/128), 256, 0, stream>>>(comp, DL, WkT, 256, knr, 1024, 256);
  gemm_bt<__bf16><<<dim3(2048/128, ROWS/128), 256, 0, stream>>>(comp + 256, DL, WvT, 256, vb, 2048, 256);

  rope_assemble<<<ROWS * NH, 64, 0, stream>>>(qnr, qr, qfull);
  rope_assemble<<<ROWS * NH, 64, 0, stream>>>(knr, kr, kfull);
  transpose_v<<<dim3(SEQ/32, 128/32, NB*NH), tb, 0, stream>>>(vb, vtr);

  attn_fwd<<<dim3(SEQ/128, NH, NB), 256, 0, stream>>>(qfull, kfull, vtr, ctx);

  gemm_bt<float><<<dim3(2048/128, ROWS/128), 256, 0, stream>>>(ctx, DM, WoT, DM, out, 2048, DM);
}

// Round 5
// 403.561 us; speedup vs baseline: 2.2127x; 1.2395x over previous
//
#include <hip/hip_runtime.h>
#include <stdint.h>

typedef __bf16 bf16x8 __attribute__((ext_vector_type(8)));
typedef __bf16 bf16x4 __attribute__((ext_vector_type(4)));
typedef float f32x4 __attribute__((ext_vector_type(4)));
typedef float f32x16 __attribute__((ext_vector_type(16)));

constexpr int NB   = 2;      // batch
constexpr int SEQ  = 2048;   // sequence
constexpr int DM   = 2048;   // d_model
constexpr int NH   = 16;     // heads
constexpr int HD   = 128;    // head dim
constexpr int DL   = 512;    // d_latent
constexpr int ROWS = NB * SEQ; // 4096

// async global->LDS, 16B per lane; LDS dest = wave-uniform base + lane*16
__device__ __forceinline__ void gload16(const void* g, void* l) {
  __builtin_amdgcn_global_load_lds((const __attribute__((address_space(1))) uint32_t*)(const void*)g,
                                   (__attribute__((address_space(3))) uint32_t*)(void*)l, 16, 0, 0);
}

__device__ __forceinline__ uint32_t pk2(float lo, float hi) {
  union { __bf16 h[2]; uint32_t u; } x;
  x.h[0] = (__bf16)lo; x.h[1] = (__bf16)hi;
  return x.u;
}

// ---------------------------------------------------------------- cast f32->bf16
__global__ __launch_bounds__(256) void cast_bf16(const float* __restrict__ in,
                                                 __bf16* __restrict__ out, int n4) {
  int i = blockIdx.x * blockDim.x + threadIdx.x;
  int stride = gridDim.x * blockDim.x;
  for (int k = i; k < n4; k += stride) {
    float4 v = ((const float4*)in)[k];
    union { __bf16 h[4]; uint2 u; } uo;
    uo.h[0] = (__bf16)v.x; uo.h[1] = (__bf16)v.y;
    uo.h[2] = (__bf16)v.z; uo.h[3] = (__bf16)v.w;
    ((uint2*)out)[k] = uo.u;
  }
}

// ------------------------------------------------- tiled transpose + cast f32->bf16
__global__ __launch_bounds__(256) void transpose_cast(const float* __restrict__ in,
                                                      __bf16* __restrict__ out,
                                                      int R, int C) {
  __shared__ float t[32][33];
  int r0 = blockIdx.y * 32, c0 = blockIdx.x * 32;
  int tx = threadIdx.x, ty = threadIdx.y;
#pragma unroll
  for (int i = 0; i < 4; ++i)
    t[ty + 8*i][tx] = in[(size_t)(r0 + ty + 8*i) * C + c0 + tx];
  __syncthreads();
#pragma unroll
  for (int i = 0; i < 4; ++i)
    out[(size_t)(c0 + ty + 8*i) * R + r0 + tx] = (__bf16)t[tx][ty + 8*i];
}

// ------------------------------------------------- tiled bf16 transpose for V
// v: [b][s][h*128+d] -> vt: [b][h][d][s]
__global__ __launch_bounds__(256) void transpose_v(const __bf16* __restrict__ v,
                                                   __bf16* __restrict__ vt) {
  __shared__ __bf16 t[32][33];
  int b = blockIdx.z >> 4, h = blockIdx.z & 15;
  int s0 = blockIdx.x * 32, d0 = blockIdx.y * 32;
  int tx = threadIdx.x, ty = threadIdx.y;
#pragma unroll
  for (int i = 0; i < 4; ++i)
    t[ty + 8*i][tx] = v[(size_t)(b*SEQ + s0 + ty + 8*i) * 2048 + h*128 + d0 + tx];
  __syncthreads();
#pragma unroll
  for (int i = 0; i < 4; ++i)
    vt[((size_t)(b*NH + h) * 128 + d0 + ty + 8*i) * 2048 + s0 + tx] = t[tx][ty + 8*i];
}

// ------------------------------------------------- generic GEMM:  C[m][n] = sum_k A[m][k]*Bt[n][k]
// 128x128 tile, BK=64, 4 waves (2x2), global_load_lds staging, T2 XOR-swizzled LDS
// (byte ^= (row&7)<<4; linear dest + inverse-swizzled source + swizzled reads)
template <typename CT>
__global__ __launch_bounds__(256) void gemm_bt(const __bf16* __restrict__ A, int lda,
                                               const __bf16* __restrict__ Bt, int ldb,
                                               CT* __restrict__ C, int ldc, int K_) {
  __shared__ __align__(16) char As[16384];  // [128][64] bf16, 128B rows, swizzled
  __shared__ __align__(16) char Bs[16384];
  const int m0 = blockIdx.y * 128, n0 = blockIdx.x * 128;
  const int t = threadIdx.x;
  const int wid = t >> 6, lane = t & 63;
  const int wr = (wid >> 1) * 64, wc = (wid & 1) * 64;
  const int lr = lane & 15, lg = lane >> 4;
  f32x4 acc[4][4] = {};
  for (int k0 = 0; k0 < K_; k0 += 64) {
    __syncthreads();  // readers of previous tile done
#pragma unroll
    for (int i = 0; i < 4; ++i) {
      int obi = wid * 4096 + i * 1024;     // wave-uniform LDS byte base
      int o   = obi + lane * 16;           // linear LDS byte this lane fills
      int row = o >> 7, sb = o & 127;
      int cb  = sb ^ ((row & 7) << 4);     // inverse swizzle on the SOURCE
      gload16((const char*)A  + ((size_t)(m0 + row) * lda + k0) * 2 + cb, As + obi);
      gload16((const char*)Bt + ((size_t)(n0 + row) * ldb + k0) * 2 + cb, Bs + obi);
    }
    __syncthreads();  // drains vmcnt -> staging complete
#pragma unroll
    for (int kk = 0; kk < 2; ++kk) {
      bf16x8 af[4], bfr[4];
#pragma unroll
      for (int mi = 0; mi < 4; ++mi) {
        int row = wr + mi*16 + lr;
        af[mi] = *(const bf16x8*)(As + row * 128 + ((kk*64 + 16*lg) ^ ((row & 7) << 4)));
      }
#pragma unroll
      for (int ni = 0; ni < 4; ++ni) {
        int row = wc + ni*16 + lr;
        bfr[ni] = *(const bf16x8*)(Bs + row * 128 + ((kk*64 + 16*lg) ^ ((row & 7) << 4)));
      }
#pragma unroll
      for (int mi = 0; mi < 4; ++mi)
#pragma unroll
        for (int ni = 0; ni < 4; ++ni)
          acc[mi][ni] = __builtin_amdgcn_mfma_f32_16x16x32_bf16(af[mi], bfr[ni], acc[mi][ni], 0, 0, 0);
    }
  }
#pragma unroll
  for (int mi = 0; mi < 4; ++mi)
#pragma unroll
    for (int ni = 0; ni < 4; ++ni) {
      int r = m0 + wr + mi*16 + lg*4;
      int c = n0 + wc + ni*16 + lr;
#pragma unroll
      for (int j = 0; j < 4; ++j)
        C[(size_t)(r + j) * ldc + c] = (CT)acc[mi][ni][j];
    }
}

// ------------------------------------------------- RoPE + concat-assemble (one block per bs row)
// nr/rp: row stride ld; out full row = [nr(0..1023) | rp(0..1023)] with RoPE on
// d in [64,128) of each 128-head-block; entire output scaled by SC.
__global__ __launch_bounds__(256) void rope_assemble(const __bf16* __restrict__ nr,
                                                     const __bf16* __restrict__ rp,
                                                     int ld, __bf16* __restrict__ full,
                                                     float SC) {
  __shared__ float cs[32], sn[32];
  const int bs = blockIdx.x;
  const int s = bs & (SEQ - 1);
  const int t = threadIdx.x;
  if (t < 32) {
    float inv = exp2f(-0.41524101186092029f * (float)t);  // 10000^(-t/32)
    float ang = (float)s * inv;
    sincosf(ang, &sn[t], &cs[t]);
  }
  __syncthreads();
  const __bf16* nrow = nr + (size_t)bs * ld;
  const __bf16* rrow = rp + (size_t)bs * ld;
  __bf16* orow = full + (size_t)bs * 2048;
  const int c0 = t * 8;
  const __bf16* src = (c0 < 1024) ? (nrow + c0) : (rrow + (c0 - 1024));
  const int dh = c0 & 127;
  bf16x8 v = *(const bf16x8*)src;
  bf16x8 o;
  if (dh < 64) {
#pragma unroll
    for (int i = 0; i < 8; ++i) o[i] = (__bf16)((float)v[i] * SC);
  } else if (dh < 96) {
    bf16x8 v2 = *(const bf16x8*)(src + 32);
#pragma unroll
    for (int i = 0; i < 8; ++i) {
      int j = dh - 64 + i;
      o[i] = (__bf16)(((float)v[i] * cs[j] - (float)v2[i] * sn[j]) * SC);
    }
  } else {
    bf16x8 v1 = *(const bf16x8*)(src - 32);
#pragma unroll
    for (int i = 0; i < 8; ++i) {
      int j = dh - 96 + i;
      o[i] = (__bf16)(((float)v1[i] * sn[j] + (float)v[i] * cs[j]) * SC);
    }
  }
  *(bf16x8*)(orow + c0) = o;
}

// ------------------------------------------------- flash attention (32x32 swapped-QK^T)
// 4 waves/block, 32 q-rows/wave, KVBLK=64; K,V^T double-buffered, XOR-swizzled LDS.
// Q is PRE-SCALED by 1/sqrt(128). T5 setprio around MFMA clusters; T13 defer-max.
// grid (SEQ/128, NH, NB), block 256
__global__ __launch_bounds__(256, 2) void attn_fwd(const __bf16* __restrict__ qf,
                                                   const __bf16* __restrict__ kf,
                                                   const __bf16* __restrict__ vt,
                                                   __bf16* __restrict__ ctx) {
  __shared__ __align__(16) char Ks[2][16384];  // [key 0..63][d 0..127] swizzled, 256B rows
  __shared__ __align__(16) char Vs[2][16384];  // [d 0..127][key 0..63] swizzled, 128B rows
  const int t = threadIdx.x;
  const int wid = t >> 6, lane = t & 63;
  const int lq = lane & 31, hi = lane >> 5;
  const int h = blockIdx.y, b = blockIdx.z;
  const int qrow = blockIdx.x * 128 + wid * 32 + lq;
  const char* kbh = (const char*)(kf + (size_t)b * SEQ * DM + h * HD);
  const char* vbh = (const char*)(vt + (size_t)(b * NH + h) * HD * SEQ);

  bf16x8 qfr[8];
  const __bf16* qrp = qf + (size_t)(b * SEQ + qrow) * DM + h * HD;
#pragma unroll
  for (int kk = 0; kk < 8; ++kk)
    qfr[kk] = *(const bf16x8*)(qrp + kk * 16 + 8 * hi);

  f32x16 accO[4] = {};
  float mrun = -1e30f, lsum = 0.f;

  auto stageK = [&](int buf, int kc) {
#pragma unroll
    for (int i = 0; i < 4; ++i) {
      int ob = wid * 4096 + i * 1024;
      int o  = ob + lane * 16;
      int key = o >> 8, sb = o & 255;
      int cb  = sb ^ ((key & 7) << 4);
      gload16(kbh + (size_t)(kc + key) * (DM * 2) + cb, Ks[buf] + ob);
    }
  };
  auto stageV = [&](int buf, int kc) {
#pragma unroll
    for (int i = 0; i < 4; ++i) {
      int ob = wid * 4096 + i * 1024;
      int o  = ob + lane * 16;
      int d = o >> 7, sb = o & 127;
      int cb = sb ^ ((d & 7) << 4);
      gload16(vbh + (size_t)d * (SEQ * 2) + (size_t)kc * 2 + cb, Vs[buf] + ob);
    }
  };

  stageK(0, 0); stageV(0, 0);
  __syncthreads();
  int cur = 0;
  for (int kc = 0; kc < SEQ; kc += 64) {
    if (kc + 64 < SEQ) { stageK(cur ^ 1, kc + 64); stageV(cur ^ 1, kc + 64); }

    // ---- QK^T (S^T), q pre-scaled
    f32x16 st[2] = {};
    __builtin_amdgcn_s_setprio(1);
#pragma unroll
    for (int tt = 0; tt < 2; ++tt) {
      const int key = tt * 32 + lq;
      const char* kb = Ks[cur] + key * 256;
      const int swz = (key & 7) << 4;
#pragma unroll
      for (int kk = 0; kk < 8; ++kk) {
        bf16x8 kfr = *(const bf16x8*)(kb + ((32 * kk + 16 * hi) ^ swz));
        st[tt] = __builtin_amdgcn_mfma_f32_32x32x16_bf16(kfr, qfr[kk], st[tt], 0, 0, 0);
      }
    }
    __builtin_amdgcn_s_setprio(0);

    // ---- online softmax with defer-max (THR=8)
    float p[2][16];
    float cmax = -1e30f;
#pragma unroll
    for (int tt = 0; tt < 2; ++tt)
#pragma unroll
      for (int r = 0; r < 16; ++r) {
        p[tt][r] = st[tt][r];
        cmax = fmaxf(cmax, st[tt][r]);
      }
    cmax = fmaxf(cmax, __shfl_xor(cmax, 32));
    if (!__all(cmax - mrun <= 8.f)) {
      float mnew = fmaxf(mrun, cmax);
      float corr = __expf(mrun - mnew);
      lsum *= corr;
#pragma unroll
      for (int db = 0; db < 4; ++db) accO[db] *= corr;
      mrun = mnew;
    }
    float psum = 0.f;
#pragma unroll
    for (int tt = 0; tt < 2; ++tt)
#pragma unroll
      for (int r = 0; r < 16; ++r) {
        p[tt][r] = __expf(p[tt][r] - mrun);
        psum += p[tt][r];
      }
    psum += __shfl_xor(psum, 32);
    lsum += psum;

    // ---- build P B-frags in-register
    bf16x8 pfrag[4];
#pragma unroll
    for (int sl = 0; sl < 4; ++sl) {
      const int tt = sl >> 1, kk = sl & 1;
      uint32_t a0 = pk2(p[tt][8*kk + 0], p[tt][8*kk + 1]);
      uint32_t a1 = pk2(p[tt][8*kk + 2], p[tt][8*kk + 3]);
      uint32_t b0 = pk2(p[tt][8*kk + 4], p[tt][8*kk + 5]);
      uint32_t b1 = pk2(p[tt][8*kk + 6], p[tt][8*kk + 7]);
      uint32_t pa0 = (uint32_t)__shfl_xor((int)a0, 32);
      uint32_t pa1 = (uint32_t)__shfl_xor((int)a1, 32);
      uint32_t pb0 = (uint32_t)__shfl_xor((int)b0, 32);
      uint32_t pb1 = (uint32_t)__shfl_xor((int)b1, 32);
      union { uint32_t u[4]; bf16x8 v; } pu;
      pu.u[0] = hi ? pb0 : a0;
      pu.u[1] = hi ? pb1 : a1;
      pu.u[2] = hi ? b0 : pa0;
      pu.u[3] = hi ? b1 : pa1;
      pfrag[sl] = pu.v;
    }

    // ---- PV
    __builtin_amdgcn_s_setprio(1);
#pragma unroll
    for (int db = 0; db < 4; ++db) {
      const int d = db * 32 + lq;
      const char* vb = Vs[cur] + d * 128;
      const int swz = (d & 7) << 4;
#pragma unroll
      for (int sl = 0; sl < 4; ++sl) {
        bf16x8 vfr = *(const bf16x8*)(vb + ((32 * sl + 16 * hi) ^ swz));
        accO[db] = __builtin_amdgcn_mfma_f32_32x32x16_bf16(vfr, pfrag[sl], accO[db], 0, 0, 0);
      }
    }
    __builtin_amdgcn_s_setprio(0);
    __syncthreads();
    cur ^= 1;
  }

  float inv = 1.f / lsum;
  __bf16* op = ctx + (size_t)(b * SEQ + qrow) * DM + h * HD;
#pragma unroll
  for (int db = 0; db < 4; ++db)
#pragma unroll
    for (int a = 0; a < 4; ++a) {
      bf16x4 o4;
#pragma unroll
      for (int j = 0; j < 4; ++j) o4[j] = (__bf16)(accO[db][4*a + j] * inv);
      *(bf16x4*)(op + db*32 + 8*a + 4*hi) = o4;
    }
}

// ----------------------------------------------------------------------------
extern "C" void kernel_launch(void* const* d_in, const int* in_sizes, int n_in,
                              void* d_out, int out_size, void* d_ws, size_t ws_size,
                              hipStream_t stream) {
  const float* x   = (const float*)d_in[0];
  const float* Wc  = (const float*)d_in[1];
  const float* Wq  = (const float*)d_in[2];
  const float* Wk  = (const float*)d_in[3];
  const float* Wv  = (const float*)d_in[4];
  const float* Wrq = (const float*)d_in[5];
  const float* Wrk = (const float*)d_in[6];
  const float* Wo  = (const float*)d_in[7];
  float* out = (float*)d_out;

  char* ws = (char*)d_ws;
  size_t off = 0;
  auto take = [&](size_t bytes) { char* p = ws + off; off += bytes; return (__bf16*)p; };
  __bf16* xb    = take((size_t)ROWS * DM * 2);
  __bf16* comp  = take((size_t)ROWS * DL * 2);
  __bf16* qnr   = take((size_t)ROWS * 1024 * 2);  // fused [4096][2048]: qnr | knr
  __bf16* knr   = take((size_t)ROWS * 1024 * 2);
  __bf16* qr    = take((size_t)ROWS * 1024 * 2);  // fused [4096][2048]: qr | kr
  __bf16* kr    = take((size_t)ROWS * 1024 * 2);
  __bf16* vb    = take((size_t)ROWS * 2048 * 2);
  __bf16* qfull = take((size_t)ROWS * 2048 * 2);
  __bf16* kfull = take((size_t)ROWS * 2048 * 2);
  __bf16* WcT   = take((size_t)512 * 2048 * 2);
  __bf16* WqT   = take((size_t)1024 * 256 * 2);   // WqT|WkT contiguous -> 2048x256
  __bf16* WkT   = take((size_t)1024 * 256 * 2);
  __bf16* WvT   = take((size_t)2048 * 256 * 2);
  __bf16* WrqT  = take((size_t)1024 * 2048 * 2);  // WrqT|WrkT contiguous -> 2048x2048
  __bf16* WrkT  = take((size_t)1024 * 2048 * 2);
  __bf16* WoT   = take((size_t)2048 * 2048 * 2);
  (void)knr; (void)kr; (void)WkT; (void)WrkT;
  __bf16* ctx = qnr;  // alias: nr buffer dead after rope_assemble (16.8 MB)
  __bf16* vtr = qr;   // alias: rope-proj buffer dead after rope_assemble (16.8 MB)

  const float scale = 0.088388347648318447f;  // 1/sqrt(128)

  dim3 tb(32, 8);
  cast_bf16<<<4096, 256, 0, stream>>>(x, xb, ROWS * DM / 4);
  transpose_cast<<<dim3(512/32,  2048/32), tb, 0, stream>>>(Wc,  WcT,  2048, 512);
  transpose_cast<<<dim3(1024/32, 256/32),  tb, 0, stream>>>(Wq,  WqT,  256, 1024);
  transpose_cast<<<dim3(1024/32, 256/32),  tb, 0, stream>>>(Wk,  WkT,  256, 1024);
  transpose_cast<<<dim3(2048/32, 256/32),  tb, 0, stream>>>(Wv,  WvT,  256, 2048);
  transpose_cast<<<dim3(1024/32, 2048/32), tb, 0, stream>>>(Wrq, WrqT, 2048, 1024);
  transpose_cast<<<dim3(1024/32, 2048/32), tb, 0, stream>>>(Wrk, WrkT, 2048, 1024);
  transpose_cast<<<dim3(2048/32, 2048/32), tb, 0, stream>>>(Wo,  WoT,  2048, 2048);

  // compressed = x @ W_comp
  gemm_bt<__bf16><<<dim3(512/128, ROWS/128), 256, 0, stream>>>(xb, DM, WcT, DM, comp, DL, DM);
  // fused rope projections: [q_rope | k_rope] = x @ [W_rope_q | W_rope_k]
  gemm_bt<__bf16><<<dim3(2048/128, ROWS/128), 256, 0, stream>>>(xb, DM, WrqT, DM, qr, 2048, DM);
  // fused decode: [q_no_rope | k_no_rope] = c_qk @ [W_q_dec | W_k_dec]
  gemm_bt<__bf16><<<dim3(2048/128, ROWS/128), 256, 0, stream>>>(comp, DL, WqT, 256, qnr, 2048, 256);
  // v = c_v @ W_v_dec
  gemm_bt<__bf16><<<dim3(2048/128, ROWS/128), 256, 0, stream>>>(comp + 256, DL, WvT, 256, vb, 2048, 256);

  rope_assemble<<<ROWS, 256, 0, stream>>>(qnr,        qr,        2048, qfull, scale);
  rope_assemble<<<ROWS, 256, 0, stream>>>(qnr + 1024, qr + 1024, 2048, kfull, 1.0f);
  transpose_v<<<dim3(SEQ/32, 128/32, NB*NH), tb, 0, stream>>>(vb, vtr);

  attn_fwd<<<dim3(SEQ/128, NH, NB), 256, 0, stream>>>(qfull, kfull, vtr, ctx);

  gemm_bt<float><<<dim3(2048/128, ROWS/128), 256, 0, stream>>>(ctx, DM, WoT, DM, out, 2048, DM);
}

// Round 6
// 400.751 us; speedup vs baseline: 2.2282x; 1.0070x over previous
//
#include <hip/hip_runtime.h>
#include <stdint.h>

typedef __bf16 bf16x8 __attribute__((ext_vector_type(8)));
typedef __bf16 bf16x4 __attribute__((ext_vector_type(4)));
typedef float f32x4 __attribute__((ext_vector_type(4)));
typedef float f32x16 __attribute__((ext_vector_type(16)));

constexpr int NB   = 2;      // batch
constexpr int SEQ  = 2048;   // sequence
constexpr int DM   = 2048;   // d_model
constexpr int NH   = 16;     // heads
constexpr int HD   = 128;    // head dim
constexpr int DL   = 512;    // d_latent
constexpr int ROWS = NB * SEQ; // 4096

// async global->LDS, 16B per lane; LDS dest = wave-uniform base + lane*16
__device__ __forceinline__ void gload16(const void* g, void* l) {
  __builtin_amdgcn_global_load_lds((const __attribute__((address_space(1))) uint32_t*)(const void*)g,
                                   (__attribute__((address_space(3))) uint32_t*)(void*)l, 16, 0, 0);
}

__device__ __forceinline__ uint32_t pk2(float lo, float hi) {
  union { __bf16 h[2]; uint32_t u; } x;
  x.h[0] = (__bf16)lo; x.h[1] = (__bf16)hi;
  return x.u;
}

// ---------------------------------------------------------------- cast f32->bf16
__global__ __launch_bounds__(256) void cast_bf16(const float* __restrict__ in,
                                                 __bf16* __restrict__ out, int n4) {
  int i = blockIdx.x * blockDim.x + threadIdx.x;
  int stride = gridDim.x * blockDim.x;
  for (int k = i; k < n4; k += stride) {
    float4 v = ((const float4*)in)[k];
    union { __bf16 h[4]; uint2 u; } uo;
    uo.h[0] = (__bf16)v.x; uo.h[1] = (__bf16)v.y;
    uo.h[2] = (__bf16)v.z; uo.h[3] = (__bf16)v.w;
    ((uint2*)out)[k] = uo.u;
  }
}

// ------------------------------------------------- merged tiled transpose + cast (7 weights)
struct TC7 {
  const float* in[7];
  __bf16* out[7];
  int R[7], C[7];
};
// out[c][r] = in[r][c];  grid (64, 64, 7), block (32,8); early-out past dims
__global__ __launch_bounds__(256) void transpose_cast7(TC7 d) {
  const int z = blockIdx.z;
  const int R = d.R[z], C = d.C[z];
  const int r0 = blockIdx.y * 32, c0 = blockIdx.x * 32;
  if (r0 >= R || c0 >= C) return;
  __shared__ float t[32][33];
  const float* in = d.in[z];
  __bf16* out = d.out[z];
  int tx = threadIdx.x, ty = threadIdx.y;
#pragma unroll
  for (int i = 0; i < 4; ++i)
    t[ty + 8*i][tx] = in[(size_t)(r0 + ty + 8*i) * C + c0 + tx];
  __syncthreads();
#pragma unroll
  for (int i = 0; i < 4; ++i)
    out[(size_t)(c0 + ty + 8*i) * R + r0 + tx] = (__bf16)t[tx][ty + 8*i];
}

// ------------------------------------------------- tiled bf16 transpose for V
// v: [b][s][h*128+d] -> vt: [b][h][d][s]
__global__ __launch_bounds__(256) void transpose_v(const __bf16* __restrict__ v,
                                                   __bf16* __restrict__ vt) {
  __shared__ __bf16 t[32][33];
  int b = blockIdx.z >> 4, h = blockIdx.z & 15;
  int s0 = blockIdx.x * 32, d0 = blockIdx.y * 32;
  int tx = threadIdx.x, ty = threadIdx.y;
#pragma unroll
  for (int i = 0; i < 4; ++i)
    t[ty + 8*i][tx] = v[(size_t)(b*SEQ + s0 + ty + 8*i) * 2048 + h*128 + d0 + tx];
  __syncthreads();
#pragma unroll
  for (int i = 0; i < 4; ++i)
    vt[((size_t)(b*NH + h) * 128 + d0 + ty + 8*i) * 2048 + s0 + tx] = t[tx][ty + 8*i];
}

// ------------------------------------------------- generic GEMM:  C[m][n] = sum_k A[m][k]*Bt[n][k]
// 128x128 tile, BK=64, 4 waves (2x2), global_load_lds staging, T2 XOR-swizzled LDS.
// Epilogue: LDS-bounce -> coalesced vector stores (bf16x8 / f32x4 rows).
template <typename CT>
__global__ __launch_bounds__(256) void gemm_bt(const __bf16* __restrict__ A, int lda,
                                               const __bf16* __restrict__ Bt, int ldb,
                                               CT* __restrict__ C, int ldc, int K_) {
  __shared__ __align__(16) char smem[32768];
  char* As = smem;            // [128][64] bf16, 128B rows, swizzled
  char* Bs = smem + 16384;
  const int m0 = blockIdx.y * 128, n0 = blockIdx.x * 128;
  const int t = threadIdx.x;
  const int wid = t >> 6, lane = t & 63;
  const int wr = (wid >> 1) * 64, wc = (wid & 1) * 64;
  const int lr = lane & 15, lg = lane >> 4;
  f32x4 acc[4][4] = {};
  for (int k0 = 0; k0 < K_; k0 += 64) {
    __syncthreads();  // readers of previous tile done
#pragma unroll
    for (int i = 0; i < 4; ++i) {
      int obi = wid * 4096 + i * 1024;     // wave-uniform LDS byte base
      int o   = obi + lane * 16;           // linear LDS byte this lane fills
      int row = o >> 7, sb = o & 127;
      int cb  = sb ^ ((row & 7) << 4);     // inverse swizzle on the SOURCE
      gload16((const char*)A  + ((size_t)(m0 + row) * lda + k0) * 2 + cb, As + obi);
      gload16((const char*)Bt + ((size_t)(n0 + row) * ldb + k0) * 2 + cb, Bs + obi);
    }
    __syncthreads();  // drains vmcnt -> staging complete
#pragma unroll
    for (int kk = 0; kk < 2; ++kk) {
      bf16x8 af[4], bfr[4];
#pragma unroll
      for (int mi = 0; mi < 4; ++mi) {
        int row = wr + mi*16 + lr;
        af[mi] = *(const bf16x8*)(As + row * 128 + ((kk*64 + 16*lg) ^ ((row & 7) << 4)));
      }
#pragma unroll
      for (int ni = 0; ni < 4; ++ni) {
        int row = wc + ni*16 + lr;
        bfr[ni] = *(const bf16x8*)(Bs + row * 128 + ((kk*64 + 16*lg) ^ ((row & 7) << 4)));
      }
#pragma unroll
      for (int mi = 0; mi < 4; ++mi)
#pragma unroll
        for (int ni = 0; ni < 4; ++ni)
          acc[mi][ni] = __builtin_amdgcn_mfma_f32_16x16x32_bf16(af[mi], bfr[ni], acc[mi][ni], 0, 0, 0);
    }
  }
  // ---- epilogue: bounce each 16x64 sub-tile through LDS for coalesced stores
  __syncthreads();  // all waves done reading As/Bs
  float* Lf = (float*)(smem + wid * 8192);  // [16][68] f32, padded
#pragma unroll
  for (int mi = 0; mi < 4; ++mi) {
#pragma unroll
    for (int ni = 0; ni < 4; ++ni)
#pragma unroll
      for (int j = 0; j < 4; ++j)
        Lf[(lg*4 + j) * 68 + ni*16 + lr] = acc[mi][ni][j];
    // readback: lane -> row lr, cols [lg*16, lg*16+16)
    CT* Cp = C + (size_t)(m0 + wr + mi*16 + lr) * ldc + n0 + wc + lg*16;
    if constexpr (sizeof(CT) == 2) {
      union { __bf16 h[8]; uint4 q; } o0, o1;
#pragma unroll
      for (int u = 0; u < 8; ++u) {
        o0.h[u] = (__bf16)Lf[lr*68 + lg*16 + u];
        o1.h[u] = (__bf16)Lf[lr*68 + lg*16 + 8 + u];
      }
      *(uint4*)(Cp)     = o0.q;
      *(uint4*)(Cp + 8) = o1.q;
    } else {
#pragma unroll
      for (int u = 0; u < 4; ++u)
        *(f32x4*)(Cp + 4*u) = *(const f32x4*)&Lf[lr*68 + lg*16 + 4*u];
    }
    if (mi < 3) __syncthreads();  // region reuse across mi (cheap, keeps waves aligned)
  }
}

// ------------------------------------------------- RoPE + concat-assemble (q and k in one grid)
// y==0: q (scaled by 1/sqrt(128)) from (nr, rp); y==1: k from (nr+1024, rp+1024).
__global__ __launch_bounds__(256) void rope_assemble2(const __bf16* __restrict__ nr0,
                                                      const __bf16* __restrict__ rp0,
                                                      __bf16* __restrict__ qfull,
                                                      __bf16* __restrict__ kfull,
                                                      float qsc) {
  __shared__ float cs[32], sn[32];
  const int bs = blockIdx.x;
  const int which = blockIdx.y;
  const int s = bs & (SEQ - 1);
  const int t = threadIdx.x;
  if (t < 32) {
    float inv = exp2f(-0.41524101186092029f * (float)t);  // 10000^(-t/32)
    float ang = (float)s * inv;
    sincosf(ang, &sn[t], &cs[t]);
  }
  __syncthreads();
  const float SC = which ? 1.0f : qsc;
  const __bf16* nrow = nr0 + which * 1024 + (size_t)bs * 2048;
  const __bf16* rrow = rp0 + which * 1024 + (size_t)bs * 2048;
  __bf16* orow = (which ? kfull : qfull) + (size_t)bs * 2048;
  const int c0 = t * 8;
  const __bf16* src = (c0 < 1024) ? (nrow + c0) : (rrow + (c0 - 1024));
  const int dh = c0 & 127;
  bf16x8 v = *(const bf16x8*)src;
  bf16x8 o;
  if (dh < 64) {
#pragma unroll
    for (int i = 0; i < 8; ++i) o[i] = (__bf16)((float)v[i] * SC);
  } else if (dh < 96) {
    bf16x8 v2 = *(const bf16x8*)(src + 32);
#pragma unroll
    for (int i = 0; i < 8; ++i) {
      int j = dh - 64 + i;
      o[i] = (__bf16)(((float)v[i] * cs[j] - (float)v2[i] * sn[j]) * SC);
    }
  } else {
    bf16x8 v1 = *(const bf16x8*)(src - 32);
#pragma unroll
    for (int i = 0; i < 8; ++i) {
      int j = dh - 96 + i;
      o[i] = (__bf16)(((float)v1[i] * sn[j] + (float)v[i] * cs[j]) * SC);
    }
  }
  *(bf16x8*)(orow + c0) = o;
}

// ------------------------------------------------- flash attention (32x32 swapped-QK^T)
// 4 waves/block, 32 q-rows/wave, KVBLK=64; K,V^T double-buffered, XOR-swizzled LDS.
// Q is PRE-SCALED by 1/sqrt(128). T5 setprio around MFMA clusters; T13 defer-max.
// grid (SEQ/128, NH, NB), block 256
__global__ __launch_bounds__(256, 2) void attn_fwd(const __bf16* __restrict__ qf,
                                                   const __bf16* __restrict__ kf,
                                                   const __bf16* __restrict__ vt,
                                                   __bf16* __restrict__ ctx) {
  __shared__ __align__(16) char Ks[2][16384];  // [key 0..63][d 0..127] swizzled, 256B rows
  __shared__ __align__(16) char Vs[2][16384];  // [d 0..127][key 0..63] swizzled, 128B rows
  const int t = threadIdx.x;
  const int wid = t >> 6, lane = t & 63;
  const int lq = lane & 31, hi = lane >> 5;
  const int h = blockIdx.y, b = blockIdx.z;
  const int qrow = blockIdx.x * 128 + wid * 32 + lq;
  const char* kbh = (const char*)(kf + (size_t)b * SEQ * DM + h * HD);
  const char* vbh = (const char*)(vt + (size_t)(b * NH + h) * HD * SEQ);

  bf16x8 qfr[8];
  const __bf16* qrp = qf + (size_t)(b * SEQ + qrow) * DM + h * HD;
#pragma unroll
  for (int kk = 0; kk < 8; ++kk)
    qfr[kk] = *(const bf16x8*)(qrp + kk * 16 + 8 * hi);

  f32x16 accO[4] = {};
  float mrun = -1e30f, lsum = 0.f;

  auto stageK = [&](int buf, int kc) {
#pragma unroll
    for (int i = 0; i < 4; ++i) {
      int ob = wid * 4096 + i * 1024;
      int o  = ob + lane * 16;
      int key = o >> 8, sb = o & 255;
      int cb  = sb ^ ((key & 7) << 4);
      gload16(kbh + (size_t)(kc + key) * (DM * 2) + cb, Ks[buf] + ob);
    }
  };
  auto stageV = [&](int buf, int kc) {
#pragma unroll
    for (int i = 0; i < 4; ++i) {
      int ob = wid * 4096 + i * 1024;
      int o  = ob + lane * 16;
      int d = o >> 7, sb = o & 127;
      int cb = sb ^ ((d & 7) << 4);
      gload16(vbh + (size_t)d * (SEQ * 2) + (size_t)kc * 2 + cb, Vs[buf] + ob);
    }
  };

  stageK(0, 0); stageV(0, 0);
  __syncthreads();
  int cur = 0;
  for (int kc = 0; kc < SEQ; kc += 64) {
    if (kc + 64 < SEQ) { stageK(cur ^ 1, kc + 64); stageV(cur ^ 1, kc + 64); }

    // ---- QK^T (S^T), q pre-scaled
    f32x16 st[2] = {};
    __builtin_amdgcn_s_setprio(1);
#pragma unroll
    for (int tt = 0; tt < 2; ++tt) {
      const int key = tt * 32 + lq;
      const char* kb = Ks[cur] + key * 256;
      const int swz = (key & 7) << 4;
#pragma unroll
      for (int kk = 0; kk < 8; ++kk) {
        bf16x8 kfr = *(const bf16x8*)(kb + ((32 * kk + 16 * hi) ^ swz));
        st[tt] = __builtin_amdgcn_mfma_f32_32x32x16_bf16(kfr, qfr[kk], st[tt], 0, 0, 0);
      }
    }
    __builtin_amdgcn_s_setprio(0);

    // ---- online softmax with defer-max (THR=8)
    float p[2][16];
    float cmax = -1e30f;
#pragma unroll
    for (int tt = 0; tt < 2; ++tt)
#pragma unroll
      for (int r = 0; r < 16; ++r) {
        p[tt][r] = st[tt][r];
        cmax = fmaxf(cmax, st[tt][r]);
      }
    cmax = fmaxf(cmax, __shfl_xor(cmax, 32));
    if (!__all(cmax - mrun <= 8.f)) {
      float mnew = fmaxf(mrun, cmax);
      float corr = __expf(mrun - mnew);
      lsum *= corr;
#pragma unroll
      for (int db = 0; db < 4; ++db) accO[db] *= corr;
      mrun = mnew;
    }
    float psum = 0.f;
#pragma unroll
    for (int tt = 0; tt < 2; ++tt)
#pragma unroll
      for (int r = 0; r < 16; ++r) {
        p[tt][r] = __expf(p[tt][r] - mrun);
        psum += p[tt][r];
      }
    psum += __shfl_xor(psum, 32);
    lsum += psum;

    // ---- build P B-frags in-register
    bf16x8 pfrag[4];
#pragma unroll
    for (int sl = 0; sl < 4; ++sl) {
      const int tt = sl >> 1, kk = sl & 1;
      uint32_t a0 = pk2(p[tt][8*kk + 0], p[tt][8*kk + 1]);
      uint32_t a1 = pk2(p[tt][8*kk + 2], p[tt][8*kk + 3]);
      uint32_t b0 = pk2(p[tt][8*kk + 4], p[tt][8*kk + 5]);
      uint32_t b1 = pk2(p[tt][8*kk + 6], p[tt][8*kk + 7]);
      uint32_t pa0 = (uint32_t)__shfl_xor((int)a0, 32);
      uint32_t pa1 = (uint32_t)__shfl_xor((int)a1, 32);
      uint32_t pb0 = (uint32_t)__shfl_xor((int)b0, 32);
      uint32_t pb1 = (uint32_t)__shfl_xor((int)b1, 32);
      union { uint32_t u[4]; bf16x8 v; } pu;
      pu.u[0] = hi ? pb0 : a0;
      pu.u[1] = hi ? pb1 : a1;
      pu.u[2] = hi ? b0 : pa0;
      pu.u[3] = hi ? b1 : pa1;
      pfrag[sl] = pu.v;
    }

    // ---- PV
    __builtin_amdgcn_s_setprio(1);
#pragma unroll
    for (int db = 0; db < 4; ++db) {
      const int d = db * 32 + lq;
      const char* vb = Vs[cur] + d * 128;
      const int swz = (d & 7) << 4;
#pragma unroll
      for (int sl = 0; sl < 4; ++sl) {
        bf16x8 vfr = *(const bf16x8*)(vb + ((32 * sl + 16 * hi) ^ swz));
        accO[db] = __builtin_amdgcn_mfma_f32_32x32x16_bf16(vfr, pfrag[sl], accO[db], 0, 0, 0);
      }
    }
    __builtin_amdgcn_s_setprio(0);
    __syncthreads();
    cur ^= 1;
  }

  float inv = 1.f / lsum;
  __bf16* op = ctx + (size_t)(b * SEQ + qrow) * DM + h * HD;
#pragma unroll
  for (int db = 0; db < 4; ++db)
#pragma unroll
    for (int a = 0; a < 4; ++a) {
      bf16x4 o4;
#pragma unroll
      for (int j = 0; j < 4; ++j) o4[j] = (__bf16)(accO[db][4*a + j] * inv);
      *(bf16x4*)(op + db*32 + 8*a + 4*hi) = o4;
    }
}

// ----------------------------------------------------------------------------
extern "C" void kernel_launch(void* const* d_in, const int* in_sizes, int n_in,
                              void* d_out, int out_size, void* d_ws, size_t ws_size,
                              hipStream_t stream) {
  const float* x   = (const float*)d_in[0];
  const float* Wc  = (const float*)d_in[1];
  const float* Wq  = (const float*)d_in[2];
  const float* Wk  = (const float*)d_in[3];
  const float* Wv  = (const float*)d_in[4];
  const float* Wrq = (const float*)d_in[5];
  const float* Wrk = (const float*)d_in[6];
  const float* Wo  = (const float*)d_in[7];
  float* out = (float*)d_out;

  char* ws = (char*)d_ws;
  size_t off = 0;
  auto take = [&](size_t bytes) { char* p = ws + off; off += bytes; return (__bf16*)p; };
  __bf16* xb    = take((size_t)ROWS * DM * 2);
  __bf16* comp  = take((size_t)ROWS * DL * 2);
  __bf16* qnr   = take((size_t)ROWS * 1024 * 2);  // fused [4096][2048]: qnr | knr
  __bf16* knr   = take((size_t)ROWS * 1024 * 2);
  __bf16* qr    = take((size_t)ROWS * 1024 * 2);  // fused [4096][2048]: qr | kr
  __bf16* kr    = take((size_t)ROWS * 1024 * 2);
  __bf16* vb    = take((size_t)ROWS * 2048 * 2);
  __bf16* qfull = take((size_t)ROWS * 2048 * 2);
  __bf16* kfull = take((size_t)ROWS * 2048 * 2);
  __bf16* WcT   = take((size_t)512 * 2048 * 2);
  __bf16* WqT   = take((size_t)1024 * 256 * 2);   // WqT|WkT contiguous -> 2048x256
  __bf16* WkT   = take((size_t)1024 * 256 * 2);
  __bf16* WvT   = take((size_t)2048 * 256 * 2);
  __bf16* WrqT  = take((size_t)1024 * 2048 * 2);  // WrqT|WrkT contiguous -> 2048x2048
  __bf16* WrkT  = take((size_t)1024 * 2048 * 2);
  __bf16* WoT   = take((size_t)2048 * 2048 * 2);
  (void)knr; (void)kr;
  __bf16* ctx = qnr;  // alias: nr buffer dead after rope_assemble (16.8 MB)
  __bf16* vtr = qr;   // alias: rope-proj buffer dead after rope_assemble (16.8 MB)

  const float scale = 0.088388347648318447f;  // 1/sqrt(128)

  dim3 tb(32, 8);
  cast_bf16<<<4096, 256, 0, stream>>>(x, xb, ROWS * DM / 4);

  TC7 td;
  td.in[0] = Wc;  td.out[0] = WcT;  td.R[0] = 2048; td.C[0] = 512;
  td.in[1] = Wq;  td.out[1] = WqT;  td.R[1] = 256;  td.C[1] = 1024;
  td.in[2] = Wk;  td.out[2] = WkT;  td.R[2] = 256;  td.C[2] = 1024;
  td.in[3] = Wv;  td.out[3] = WvT;  td.R[3] = 256;  td.C[3] = 2048;
  td.in[4] = Wrq; td.out[4] = WrqT; td.R[4] = 2048; td.C[4] = 1024;
  td.in[5] = Wrk; td.out[5] = WrkT; td.R[5] = 2048; td.C[5] = 1024;
  td.in[6] = Wo;  td.out[6] = WoT;  td.R[6] = 2048; td.C[6] = 2048;
  transpose_cast7<<<dim3(64, 64, 7), tb, 0, stream>>>(td);

  // compressed = x @ W_comp
  gemm_bt<__bf16><<<dim3(512/128, ROWS/128), 256, 0, stream>>>(xb, DM, WcT, DM, comp, DL, DM);
  // fused rope projections: [q_rope | k_rope] = x @ [W_rope_q | W_rope_k]
  gemm_bt<__bf16><<<dim3(2048/128, ROWS/128), 256, 0, stream>>>(xb, DM, WrqT, DM, qr, 2048, DM);
  // fused decode: [q_no_rope | k_no_rope] = c_qk @ [W_q_dec | W_k_dec]
  gemm_bt<__bf16><<<dim3(2048/128, ROWS/128), 256, 0, stream>>>(comp, DL, WqT, 256, qnr, 2048, 256);
  // v = c_v @ W_v_dec
  gemm_bt<__bf16><<<dim3(2048/128, ROWS/128), 256, 0, stream>>>(comp + 256, DL, WvT, 256, vb, 2048, 256);

  rope_assemble2<<<dim3(ROWS, 2), 256, 0, stream>>>(qnr, qr, qfull, kfull, scale);
  transpose_v<<<dim3(SEQ/32, 128/32, NB*NH), tb, 0, stream>>>(vb, vtr);

  attn_fwd<<<dim3(SEQ/128, NH, NB), 256, 0, stream>>>(qfull, kfull, vtr, ctx);

  gemm_bt<float><<<dim3(2048/128, ROWS/128), 256, 0, stream>>>(ctx, DM, WoT, DM, out, 2048, DM);
}